// Round 6
// baseline (180.740 us; speedup 1.0000x reference)
//
#include <hip/hip_runtime.h>
#include <math.h>

// SphereInterLoss R6: exact 10-NN via 2D (x-slab, y-sorted) pruning.
//  count_kernel: slab id by fixed N(0,1) quantile boundaries (balance is
//                perf-only), LDS-histogram + member lists (order via atomic,
//                but downstream is order-invariant).
//  yrank_kernel: per (batch,slab) pairwise y-rank (u64 keys, idx tiebreak),
//                scatter prescaled cloud (-2x,-2y,-2z,|c|^2) into padded
//                chunk layout + radii + per-chunk real-member y-edges.
//  knn_kernel  : wave = 16 consecutive y-sorted queries x 4 residue lanes.
//                Home slab then outward slabs; per slab, ballot-driven
//                y-chunk expansion from a probed start. Per-lane predicate
//                xgap^2 + ygap^2 <= k[9]; gap clamps to 0 below own yq, so
//                expansion provably covers every lane's window (exact).
//                No LDS tiles, no syncthreads, no atomics, no data shuffles
//                in the hot loop. Final 2-round shfl merge of disjoint
//                residue sets; lane sl==0 evaluates sphere distances.
//  var_kernel  : fused per-batch var(ddof=1) + mean.

#define NB 8
#define NN 4096
#define NSLAB 16
#define SLOTS 384            // per-slab capacity (mean 256, +8 sigma)
#define MAXCH 12             // SLOTS/CHUNK
#define CHUNK 32
#define TILES 24             // SLOTS/16 query tiles per slab
#define PBATCH (NSLAB * MAXCH * CHUNK)   // 6144 padded points per batch

__device__ __constant__ float BX[15] = {
    -1.53412054f, -1.15034938f, -0.88714656f, -0.67448975f, -0.48877641f,
    -0.31863936f, -0.15731068f, 0.0f, 0.15731068f, 0.31863936f,
    0.48877641f, 0.67448975f, 0.88714656f, 1.53412054f - 0.0f * 0.0f };
// note: last entry must be +1.53412054f
__device__ __constant__ float BX_FIX = 1.53412054f;

__device__ __forceinline__ float med3f(float a, float b, float c) {
    return __builtin_amdgcn_fmed3f(a, b, c);
}

__device__ __forceinline__ void insert10(float k[10], float u) {
#pragma unroll
    for (int j = 9; j >= 1; --j) k[j] = med3f(k[j - 1], k[j], u);
    k[0] = fminf(k[0], u);
}

__device__ __forceinline__ float bxv(int i) {   // boundary accessor
    return (i == 14) ? BX_FIX : BX[i];
}

// ---------------- K1: slab histogram + member lists ----------------
__global__ __launch_bounds__(256)
void count_kernel(const float4* __restrict__ sp, int* __restrict__ cnts,
                  unsigned short* __restrict__ memb) {
    __shared__ int lc[NSLAB];
    const int b = blockIdx.x;
    if (threadIdx.x < NSLAB) lc[threadIdx.x] = 0;
    __syncthreads();
    const float4* spb = sp + ((size_t)b << 12);
    for (int i = threadIdx.x; i < NN; i += 256) {
        float x = spb[i].x;
        int s = 0;
#pragma unroll
        for (int t = 0; t < 15; ++t) s += (int)(x > bxv(t));
        int pos = atomicAdd(&lc[s], 1);
        if (pos < SLOTS) memb[(b * NSLAB + s) * SLOTS + pos] = (unsigned short)i;
    }
    __syncthreads();
    if (threadIdx.x < NSLAB)
        cnts[b * NSLAB + threadIdx.x] = min(lc[threadIdx.x], SLOTS);
}

// ---------------- K2: per-slab y-rank + scatter ----------------
__global__ __launch_bounds__(256)
void yrank_kernel(const float4* __restrict__ sp, const int* __restrict__ cnts,
                  const unsigned short* __restrict__ memb,
                  float4* __restrict__ s4, float* __restrict__ srad,
                  float2* __restrict__ edges) {
    __shared__ unsigned long long keys[SLOTS];
    __shared__ float sy[SLOTS];
    const int bs = blockIdx.x;               // 0..127
    const int b = bs >> 4;
    const int cnt = cnts[bs];
    const int nch = (cnt + CHUNK - 1) >> 5;
    int pbase = 0;
    for (int j = b * NSLAB; j < bs; ++j) {
        int cj = cnts[j];
        pbase += ((cj + CHUNK - 1) >> 5) << 5;
    }
    const float4* spb = sp + ((size_t)b << 12);
    const unsigned short* mb = memb + bs * SLOTS;

    for (int i = threadIdx.x; i < SLOTS; i += 256) {
        unsigned long long kk = ~0ull;
        if (i < cnt) {
            int m = mb[i];
            unsigned u = __float_as_uint(spb[m].y);
            u = (u >> 31) ? ~u : (u | 0x80000000u);
            kk = ((unsigned long long)u << 12) | (unsigned)m;
        }
        keys[i] = kk;
    }
    __syncthreads();
    const int base = b * PBATCH + pbase;
    for (int i = threadIdx.x; i < SLOTS; i += 256) {
        if (i < cnt) {
            unsigned long long ki = keys[i];
            int r = 0;
            for (int j = 0; j < SLOTS; ++j) r += (int)(keys[j] < ki);
            int m = (int)(ki & 0xFFFull);
            float4 v = spb[m];
            float w = fmaf(v.x, v.x, fmaf(v.y, v.y, v.z * v.z));
            s4[base + r] = make_float4(-2.f * v.x, -2.f * v.y, -2.f * v.z, w);
            srad[base + r] = v.w;
            sy[r] = v.y;
        } else if (i < (nch << 5)) {
            s4[base + i] = make_float4(0.f, 0.f, 0.f, 1e30f);
            srad[base + i] = 0.f;
        }
    }
    __syncthreads();
    if ((int)threadIdx.x < nch) {
        int c = threadIdx.x;
        float lo = sy[c << 5];
        float hi = sy[min((c << 5) + CHUNK - 1, cnt - 1)];
        edges[bs * MAXCH + c] = make_float2(lo, hi);
    }
}

// ---------------- K3: knn ----------------
__global__ __launch_bounds__(256)
void knn_kernel(const float4* __restrict__ s4, const float* __restrict__ srad,
                const int* __restrict__ cnts, const float2* __restrict__ edges,
                float* __restrict__ td) {
    __shared__ int lmeta[4][48];             // per wave: cnt[16],pbase[16],cbase[16]
    const int wslot = threadIdx.x >> 6, lane = threadIdx.x & 63;
    const int wid = (blockIdx.x << 2) | wslot;
    const int bs = wid / TILES, t = wid - bs * TILES;
    const int b = bs >> 4, s = bs & 15;
    const int sl = lane & 3, qi = lane >> 2;

    if (lane < NSLAB) lmeta[wslot][lane] = cnts[(b << 4) + lane];
    if (lane < NSLAB) {
        int pb = 0, cb = 0;
        for (int j = 0; j < lane; ++j) {
            int cj = lmeta[wslot][j];
            pb += ((cj + CHUNK - 1) >> 5) << 5;
            cb += cj;
        }
        lmeta[wslot][16 + lane] = pb;
        lmeta[wslot][32 + lane] = cb;
    }
    const int cnt0 = lmeta[wslot][s];
    if (t * 16 >= cnt0) return;
    const int pb0 = lmeta[wslot][16 + s];
    const int cb0 = lmeta[wslot][32 + s];

    int ql = t * 16 + qi;
    const bool realq = ql < cnt0;
    if (!realq) ql = t * 16;                 // duplicate a real query, no write
    const int qglob = pb0 + ql;              // batch-local padded index (13 bits)
    const float4* s4b = s4 + (size_t)b * PBATCH;
    const float4 q4 = s4b[qglob];
    const float qx = -0.5f * q4.x, qy = -0.5f * q4.y, qz = -0.5f * q4.z;
    const float qw = q4.w;
    const float ymed = __shfl(qy, 34, 64);

    float k[10];
#pragma unroll
    for (int j = 0; j < 10; ++j) k[j] = __builtin_inff();

    auto scan32 = [&](int pbS, int c, bool home) {
        const int cb32 = pbS + (c << 5);
        const float4* cp = s4b + cb32;
#pragma unroll
        for (int i = 0; i < 8; ++i) {
            const int cig = cb32 + (i << 2) + sl;
            float4 cc = cp[(i << 2) + sl];
            float d2 = fmaf(cc.x, qx, fmaf(cc.y, qy, fmaf(cc.z, qz, qw + cc.w)));
            d2 = fmaxf(d2, 0.f);
            unsigned u = (__float_as_uint(d2) & 0xFFFFE000u) | (unsigned)cig;
            float uf = __uint_as_float(u);
            if (home && cig == qglob) uf = __builtin_inff();
            insert10(k, uf);
        }
    };

    auto scan_slab = [&](int sb, float xg2, int startc, bool home) {
        const int cntS = lmeta[wslot][sb];
        const int nchS = (cntS + CHUNK - 1) >> 5;
        const int pbS = lmeta[wslot][16 + sb];
        const float2* eg = edges + ((b << 4) + sb) * MAXCH;
        for (int c = startc; c < nchS; ++c) {           // upward in y
            float2 e = eg[c];
            float gy = fmaxf(e.x - qy, 0.f);
            bool act = (fmaf(gy, gy, xg2) <= k[9]);
            if (!__any(act)) break;
            scan32(pbS, c, home);
        }
        for (int c = startc - 1; c >= 0; --c) {         // downward in y
            float2 e = eg[c];
            float gy = fmaxf(qy - e.y, 0.f);
            bool act = (fmaf(gy, gy, xg2) <= k[9]);
            if (!__any(act)) break;
            scan32(pbS, c, home);
        }
    };

    auto probe = [&](int sb) -> int {
        const int cntS = lmeta[wslot][sb];
        const int nchS = (cntS + CHUNK - 1) >> 5;
        const float2* eg = edges + ((b << 4) + sb) * MAXCH;
        float p = 1.f / (1.f + __expf(-1.702f * ymed));
        int c = min(max((int)(p * (float)cntS) >> 5, 0), nchS - 1);
        while (c > 0 && ymed < eg[c].x) --c;
        while (c < nchS - 1 && ymed > eg[c].y) ++c;
        return c;
    };

    // home slab
    scan_slab(s, 0.f, min(ql >> 5, ((cnt0 + CHUNK - 1) >> 5) - 1), true);

    // outward slabs, alternating right/left, per-lane x-gap ballot
    int sR = s + 1, sL = s - 1;
    bool goR = (sR < NSLAB), goL = (sL >= 0);
    while (goR || goL) {
        if (goR) {
            float xg = bxv(sR - 1) - qx;                 // >= 0
            float xg2 = xg * xg;
            if (!__any(xg2 <= k[9])) goR = false;
            else {
                if (lmeta[wslot][sR] > 0) scan_slab(sR, xg2, probe(sR), false);
                ++sR; goR = (sR < NSLAB);
            }
        }
        if (goL) {
            float xg = qx - bxv(sL);                     // >= 0
            float xg2 = xg * xg;
            if (!__any(xg2 <= k[9])) goL = false;
            else {
                if (lmeta[wslot][sL] > 0) scan_slab(sL, xg2, probe(sL), false);
                --sL; goL = (sL >= 0);
            }
        }
    }

    // merge the 4 disjoint residue sets per query
#pragma unroll
    for (int r = 0; r < 2; ++r) {
        float f[10];
#pragma unroll
        for (int j = 0; j < 10; ++j) f[j] = __shfl_xor(k[j], 1 << r, 64);
#pragma unroll
        for (int j = 0; j < 10; ++j) insert10(k, f[j]);
    }

    if (sl == 0 && realq) {
        const float* srb = srad + (size_t)b * PBATCH;
        const float rn = srb[qglob];
        float best = __builtin_inff();
#pragma unroll
        for (int j = 0; j < 10; ++j) {
            int m = (int)(__float_as_uint(k[j]) & 0x1FFFu);
            float4 cc = s4b[m];
            float dx = fmaf(0.5f, cc.x, qx);
            float dy = fmaf(0.5f, cc.y, qy);
            float dz = fmaf(0.5f, cc.z, qz);
            float dis = sqrtf(fmaf(dx, dx, fmaf(dy, dy, dz * dz)));
            best = fminf(best, dis - (rn + srb[m]));
        }
        td[(b << 12) + cb0 + ql] = best;   // compact order; variance perm-invariant
    }
}

// ---------------- K4: fused per-batch variance (ddof=1) + mean ----------------
__global__ __launch_bounds__(512)
void var_kernel(const float* __restrict__ td, float* __restrict__ out) {
    __shared__ float part[NB];
    const int lane = threadIdx.x & 63, s = threadIdx.x >> 6;
    const float4* x4 = (const float4*)(td + ((size_t)s << 12));

    float sum = 0.f;
#pragma unroll
    for (int i = 0; i < 16; ++i) {
        float4 v = x4[lane + (i << 6)];
        sum += (v.x + v.y) + (v.z + v.w);
    }
#pragma unroll
    for (int o = 32; o > 0; o >>= 1) sum += __shfl_xor(sum, o, 64);
    const float mu = sum / (float)NN;

    float ss = 0.f;
#pragma unroll
    for (int i = 0; i < 16; ++i) {
        float4 v = x4[lane + (i << 6)];
        float d0 = v.x - mu, d1 = v.y - mu, d2 = v.z - mu, d3 = v.w - mu;
        ss = fmaf(d0, d0, ss); ss = fmaf(d1, d1, ss);
        ss = fmaf(d2, d2, ss); ss = fmaf(d3, d3, ss);
    }
#pragma unroll
    for (int o = 32; o > 0; o >>= 1) ss += __shfl_xor(ss, o, 64);
    if (lane == 0) part[s] = ss / (float)(NN - 1);
    __syncthreads();
    if (threadIdx.x == 0) {
        float tt = 0.f;
#pragma unroll
        for (int i = 0; i < NB; ++i) tt += part[i];
        out[0] = tt / (float)NB;
    }
}

extern "C" void kernel_launch(void* const* d_in, const int* in_sizes, int n_in,
                              void* d_out, int out_size, void* d_ws, size_t ws_size,
                              hipStream_t stream) {
    const float4* spheres = (const float4*)d_in[0];
    char* ws = (char*)d_ws;
    float4*         s4    = (float4*)ws;                         // 786432 B
    float*          srad  = (float*)(ws + 786432);               // 196608 B
    float2*         edges = (float2*)(ws + 983040);              //  12288 B
    int*            cnts  = (int*)(ws + 995328);                 //    512 B
    unsigned short* memb  = (unsigned short*)(ws + 995840);      // 393216 B
    float*          td    = (float*)(ws + 995840);               // overlay (memb dead after yrank)
    float*          out   = (float*)d_out;

    count_kernel<<<dim3(NB), dim3(256), 0, stream>>>(spheres, cnts, memb);
    yrank_kernel<<<dim3(NB * NSLAB), dim3(256), 0, stream>>>(spheres, cnts, memb, s4, srad, edges);
    knn_kernel<<<dim3(NB * NSLAB * TILES / 4), dim3(256), 0, stream>>>(s4, srad, cnts, edges, td);
    var_kernel<<<dim3(1), dim3(512), 0, stream>>>(td, out);
}

// Round 7
// 133.597 us; speedup vs baseline: 1.3529x; 1.3529x over previous
//
#include <hip/hip_runtime.h>
#include <math.h>

// SphereInterLoss R7: exact 10-NN, x-sorted, static window scan.
//  prep_kernel: counting-rank by x (float compares from LDS float4, quarter
//               padded, tie-break by index) -> scatter prescaled cloud
//               (-2x,-2y,-2z,|c|^2), radii, per-chunk x-edge arrays with
//               guard slots (cminx[c], cmaxx[c+2], stride 66).
//  knn_kernel : wave = 16 consecutive sorted queries x 4 residue lanes.
//               Home scan (chunk c0 +-1, 192 cands, self by index) ->
//               ONE copy-butterfly -> exact home top-10 per query -> window
//               w = sqrt(t[9]); ONE waveMin/Max -> uniform [lo,hi]. Outward
//               whole-chunk scans gated by uniform scalar edge compares
//               (prefetched, guarded). Zero ballots/reductions in hot loop.
//               Final 2-round shfl butterfly of disjoint residue sets.
//  var_kernel : fused per-batch var(ddof=1) + mean.
// Correctness: home top-10 d2 (per query) >= true 10-NN d2, so every true
// neighbor has |dx| <= w -> inside [lo,hi] -> scanned. Quantized-key
// selection (20-bit d2 | 12-bit idx) identical to R1-R5 (absmax ~0).

#define NB 8
#define NN 4096
#define NCH 64
#define EST 66          // edge array stride: 64 chunks + guard slots

__device__ __forceinline__ float med3f(float a, float b, float c) {
    return __builtin_amdgcn_fmed3f(a, b, c);
}

// branchless insert into ascending k[0..9], dropping the max
__device__ __forceinline__ void insert10(float k[10], float u) {
#pragma unroll
    for (int j = 9; j >= 1; --j) k[j] = med3f(k[j - 1], k[j], u);
    k[0] = fminf(k[0], u);
}

// ---------------- prep: counting-rank by x + scatter ----------------
__global__ __launch_bounds__(256)
void prep_kernel(const float4* __restrict__ sp, float4* __restrict__ s4,
                 float* __restrict__ srad, float* __restrict__ cminx,
                 float* __restrict__ cmaxx) {
    __shared__ float xs[4 * 1028];               // 4 quarters, +4 pad each
    const int b = blockIdx.x >> 6, qt = blockIdx.x & 63;
    const int tid = threadIdx.x;
    const float4* spb = sp + ((size_t)b << 12);
    for (int j = tid; j < NN; j += 256)
        xs[(j >> 10) * 1028 + (j & 1023)] = spb[j].x;
    if (qt == 0 && tid < 2) {                    // guard slots
        if (tid == 0) {
            cminx[b * EST + 64] = __builtin_inff();
            cminx[b * EST + 65] = __builtin_inff();
        } else {
            cmaxx[b * EST + 0] = -__builtin_inff();
            cmaxx[b * EST + 1] = -__builtin_inff();
        }
    }
    __syncthreads();

    const int e = (qt << 6) + (tid >> 2);        // element, 4 threads each
    const int part = tid & 3;
    const float xe = xs[(e >> 10) * 1028 + (e & 1023)];
    const float4* q4 = (const float4*)(xs + part * 1028);
    int cnt = 0;
    const int jb = part << 10;
#pragma unroll 4
    for (int i = 0; i < 256; ++i) {
        float4 v = q4[i];
        const int j0 = jb + (i << 2);
        cnt += (int)((v.x < xe) | ((v.x == xe) & (j0     < e)));
        cnt += (int)((v.y < xe) | ((v.y == xe) & (j0 + 1 < e)));
        cnt += (int)((v.z < xe) | ((v.z == xe) & (j0 + 2 < e)));
        cnt += (int)((v.w < xe) | ((v.w == xe) & (j0 + 3 < e)));
    }
    cnt += __shfl_xor(cnt, 1, 64);
    cnt += __shfl_xor(cnt, 2, 64);
    if (part == 0) {
        float4 s = spb[e];
        float w = fmaf(s.x, s.x, fmaf(s.y, s.y, s.z * s.z));
        const int r = cnt;                       // exact rank (permutation)
        s4[(b << 12) + r] = make_float4(-2.f * s.x, -2.f * s.y, -2.f * s.z, w);
        srad[(b << 12) + r] = s.w;
        if ((r & 63) == 0)  cminx[b * EST + (r >> 6)] = s.x;
        if ((r & 63) == 63) cmaxx[b * EST + (r >> 6) + 2] = s.x;
    }
}

// ---------------- knn ----------------
__global__ __launch_bounds__(256)
void knn_kernel(const float4* __restrict__ s4, const float* __restrict__ srad,
                const float* __restrict__ cminx, const float* __restrict__ cmaxx,
                float* __restrict__ td) {
    const int wslot = threadIdx.x >> 6, lane = threadIdx.x & 63;
    const int b = blockIdx.x >> 6;
    const int tile = (blockIdx.x & 63) | (wslot << 6);  // quartile-mixed
    const int sl = lane & 3, qi = lane >> 2;
    const float4* s4b = s4 + ((size_t)b << 12);
    const float* srb = srad + ((size_t)b << 12);
    const float* cminb = cminx + b * EST;
    const float* cmaxb = cmaxx + b * EST;

    const int qs = (tile << 4) + qi;
    const float4 q4 = s4b[qs];
    const float qx = -0.5f * q4.x, qy = -0.5f * q4.y, qz = -0.5f * q4.z;
    const float qw = q4.w;

    float k[10];
#pragma unroll
    for (int j = 0; j < 10; ++j) k[j] = __builtin_inff();

    const int c0 = tile >> 2;
    const int hc0 = max(0, c0 - 1), hc1 = min(NCH - 1, c0 + 1);

    // ---- home scan (self excluded by index)
    for (int c = hc0; c <= hc1; ++c) {
        const int cb = c << 6;
#pragma unroll 8
        for (int i = 0; i < 16; ++i) {
            const int ci = cb + (i << 2) + sl;
            float4 cc = s4b[ci];
            float d2 = fmaf(cc.x, qx, fmaf(cc.y, qy, fmaf(cc.z, qz, qw + cc.w)));
            unsigned u = (__float_as_uint(d2) & 0xFFFFF000u) | (unsigned)ci;
            float uf = (ci == qs) ? __builtin_inff() : __uint_as_float(u);
            insert10(k, uf);
        }
    }

    // ---- exact home top-10 per query (copy butterfly) -> window
    float t[10];
#pragma unroll
    for (int j = 0; j < 10; ++j) t[j] = k[j];
#pragma unroll
    for (int r = 0; r < 2; ++r) {
        float f[10];
#pragma unroll
        for (int j = 0; j < 10; ++j) f[j] = __shfl_xor(t[j], 1 << r, 64);
#pragma unroll
        for (int j = 0; j < 10; ++j) insert10(t, f[j]);
    }
    const float w = sqrtf(fmaxf(t[9], 0.f)) * 1.0002f;
    float lo = qx - w, hi = qx + w;
#pragma unroll
    for (int o = 32; o > 0; o >>= 1) {
        lo = fminf(lo, __shfl_xor(lo, o, 64));
        hi = fmaxf(hi, __shfl_xor(hi, o, 64));
    }

    // ---- outward right: chunks gated by uniform prefetched edges
    {
        int c = hc1 + 1;                       // <= 64
        float edge = cminb[c];
        while (edge <= hi) {                   // guard inf at 64/65
            float nedge = cminb[c + 1];
            const int cb = c << 6;
#pragma unroll 8
            for (int i = 0; i < 16; ++i) {
                const int ci = cb + (i << 2) + sl;
                float4 cc = s4b[ci];
                float d2 = fmaf(cc.x, qx, fmaf(cc.y, qy, fmaf(cc.z, qz, qw + cc.w)));
                unsigned u = (__float_as_uint(d2) & 0xFFFFF000u) | (unsigned)ci;
                insert10(k, __uint_as_float(u));
            }
            ++c; edge = nedge;
        }
    }
    // ---- outward left
    {
        int c = hc0 - 1;                       // >= -1
        float edge = cmaxb[c + 2];             // guard -inf at 0/1
        while (edge >= lo) {
            float nedge = cmaxb[c + 1];
            const int cb = c << 6;
#pragma unroll 8
            for (int i = 0; i < 16; ++i) {
                const int ci = cb + (i << 2) + sl;
                float4 cc = s4b[ci];
                float d2 = fmaf(cc.x, qx, fmaf(cc.y, qy, fmaf(cc.z, qz, qw + cc.w)));
                unsigned u = (__float_as_uint(d2) & 0xFFFFF000u) | (unsigned)ci;
                insert10(k, __uint_as_float(u));
            }
            --c; edge = nedge;
        }
    }

    // ---- final merge of 4 disjoint residue sets per query
#pragma unroll
    for (int r = 0; r < 2; ++r) {
        float f[10];
#pragma unroll
        for (int j = 0; j < 10; ++j) f[j] = __shfl_xor(k[j], 1 << r, 64);
#pragma unroll
        for (int j = 0; j < 10; ++j) insert10(k, f[j]);
    }

    if (sl == 0) {
        const float rn = srb[qs];
        float best = __builtin_inff();
#pragma unroll
        for (int j = 0; j < 10; ++j) {
            int m = (int)(__float_as_uint(k[j]) & 0xFFFu);
            float4 cc = s4b[m];
            float dx = fmaf(0.5f, cc.x, qx);
            float dy = fmaf(0.5f, cc.y, qy);
            float dz = fmaf(0.5f, cc.z, qz);
            float dis = sqrtf(fmaf(dx, dx, fmaf(dy, dy, dz * dz)));
            best = fminf(best, dis - (rn + srb[m]));
        }
        td[(b << 12) + qs] = best;  // sorted order; variance perm-invariant
    }
}

// ---------------- fused per-batch variance (ddof=1) + mean ----------------
__global__ __launch_bounds__(512)
void var_kernel(const float* __restrict__ td, float* __restrict__ out) {
    __shared__ float part[NB];
    const int lane = threadIdx.x & 63, s = threadIdx.x >> 6;  // wave s: batch s
    const float4* x4 = (const float4*)(td + ((size_t)s << 12));

    float sum = 0.f;
#pragma unroll
    for (int i = 0; i < 16; ++i) {
        float4 v = x4[lane + (i << 6)];
        sum += (v.x + v.y) + (v.z + v.w);
    }
#pragma unroll
    for (int o = 32; o > 0; o >>= 1) sum += __shfl_xor(sum, o, 64);
    const float mu = sum / (float)NN;

    float ss = 0.f;
#pragma unroll
    for (int i = 0; i < 16; ++i) {
        float4 v = x4[lane + (i << 6)];
        float d0 = v.x - mu, d1 = v.y - mu, d2 = v.z - mu, d3 = v.w - mu;
        ss = fmaf(d0, d0, ss); ss = fmaf(d1, d1, ss);
        ss = fmaf(d2, d2, ss); ss = fmaf(d3, d3, ss);
    }
#pragma unroll
    for (int o = 32; o > 0; o >>= 1) ss += __shfl_xor(ss, o, 64);
    if (lane == 0) part[s] = ss / (float)(NN - 1);
    __syncthreads();
    if (threadIdx.x == 0) {
        float tt = 0.f;
#pragma unroll
        for (int i = 0; i < NB; ++i) tt += part[i];
        out[0] = tt / (float)NB;
    }
}

extern "C" void kernel_launch(void* const* d_in, const int* in_sizes, int n_in,
                              void* d_out, int out_size, void* d_ws, size_t ws_size,
                              hipStream_t stream) {
    const float4* spheres = (const float4*)d_in[0];
    char* ws = (char*)d_ws;
    float4* s4    = (float4*)ws;                    // 524288 B
    float*  srad  = (float*)(ws + 524288);          // 131072 B
    float*  cminx = (float*)(ws + 655360);          //   4096 B (8*66*4 used)
    float*  cmaxx = (float*)(ws + 659456);          //   4096 B
    float*  td    = (float*)(ws + 663552);          // 131072 B
    float*  out   = (float*)d_out;

    prep_kernel<<<dim3(512), dim3(256), 0, stream>>>(spheres, s4, srad, cminx, cmaxx);
    knn_kernel<<<dim3(512), dim3(256), 0, stream>>>(s4, srad, cminx, cmaxx, td);
    var_kernel<<<dim3(1), dim3(512), 0, stream>>>(td, out);
}

// Round 8
// 103.945 us; speedup vs baseline: 1.7388x; 1.2853x over previous
//
#include <hip/hip_runtime.h>
#include <math.h>

// SphereInterLoss R8: exact 10-NN, x-sorted, static window scan, full occupancy.
//  prep_kernel: counting-rank by x (LDS float4 compares, tie-break by index)
//               -> prescaled sorted cloud (-2x,-2y,-2z,|c|^2), radii,
//               per-chunk x-edge arrays with guard slots.
//  knn_kernel : wave = 4 consecutive sorted queries x 16 residue lanes
//               (8192 waves = 8 waves/SIMD -> latency actually hidden).
//               Home scan (chunk c0 +-1, self by index) -> 4-round copy
//               butterfly -> exact home top-10 -> window w = sqrt(t[9]);
//               waveMin/Max -> uniform [lo,hi]. Outward whole-chunk scans
//               gated by uniform prefetched edge compares. Zero ballots or
//               reductions in the hot loop. Final 4-round butterfly of
//               disjoint residue sets.
//  var_kernel : fused per-batch var(ddof=1) + mean.
// Correctness: per-query home top-10 d2 >= true 10-NN d2 -> every true
// neighbor lies in [lo,hi] -> scanned. Key = (d2 bits & ~0xFFF) | sorted idx.

#define NB 8
#define NN 4096
#define NCH 64
#define EST 66          // edge array stride: 64 chunks + guard slots

__device__ __forceinline__ float med3f(float a, float b, float c) {
    return __builtin_amdgcn_fmed3f(a, b, c);
}

// branchless insert into ascending k[0..9], dropping the max
__device__ __forceinline__ void insert10(float k[10], float u) {
#pragma unroll
    for (int j = 9; j >= 1; --j) k[j] = med3f(k[j - 1], k[j], u);
    k[0] = fminf(k[0], u);
}

// ---------------- prep: counting-rank by x + scatter ----------------
__global__ __launch_bounds__(256)
void prep_kernel(const float4* __restrict__ sp, float4* __restrict__ s4,
                 float* __restrict__ srad, float* __restrict__ cminx,
                 float* __restrict__ cmaxx) {
    __shared__ float xs[4 * 1028];               // 4 quarters, +4 pad each
    const int b = blockIdx.x >> 6, qt = blockIdx.x & 63;
    const int tid = threadIdx.x;
    const float4* spb = sp + ((size_t)b << 12);
    for (int j = tid; j < NN; j += 256)
        xs[(j >> 10) * 1028 + (j & 1023)] = spb[j].x;
    if (qt == 0 && tid < 2) {                    // guard slots
        if (tid == 0) {
            cminx[b * EST + 64] = __builtin_inff();
            cminx[b * EST + 65] = __builtin_inff();
        } else {
            cmaxx[b * EST + 0] = -__builtin_inff();
            cmaxx[b * EST + 1] = -__builtin_inff();
        }
    }
    __syncthreads();

    const int e = (qt << 6) + (tid >> 2);        // element, 4 threads each
    const int part = tid & 3;
    const float xe = xs[(e >> 10) * 1028 + (e & 1023)];
    const float4* q4 = (const float4*)(xs + part * 1028);
    int cnt = 0;
    const int jb = part << 10;
#pragma unroll 4
    for (int i = 0; i < 256; ++i) {
        float4 v = q4[i];
        const int j0 = jb + (i << 2);
        cnt += (int)((v.x < xe) | ((v.x == xe) & (j0     < e)));
        cnt += (int)((v.y < xe) | ((v.y == xe) & (j0 + 1 < e)));
        cnt += (int)((v.z < xe) | ((v.z == xe) & (j0 + 2 < e)));
        cnt += (int)((v.w < xe) | ((v.w == xe) & (j0 + 3 < e)));
    }
    cnt += __shfl_xor(cnt, 1, 64);
    cnt += __shfl_xor(cnt, 2, 64);
    if (part == 0) {
        float4 s = spb[e];
        float w = fmaf(s.x, s.x, fmaf(s.y, s.y, s.z * s.z));
        const int r = cnt;                       // exact rank (permutation)
        s4[(b << 12) + r] = make_float4(-2.f * s.x, -2.f * s.y, -2.f * s.z, w);
        srad[(b << 12) + r] = s.w;
        if ((r & 63) == 0)  cminx[b * EST + (r >> 6)] = s.x;
        if ((r & 63) == 63) cmaxx[b * EST + (r >> 6) + 2] = s.x;
    }
}

// ---------------- knn ----------------
__global__ __launch_bounds__(256)
void knn_kernel(const float4* __restrict__ s4, const float* __restrict__ srad,
                const float* __restrict__ cminx, const float* __restrict__ cmaxx,
                float* __restrict__ td) {
    const int wslot = threadIdx.x >> 6, lane = threadIdx.x & 63;
    const int wid = (blockIdx.x << 2) | wslot;       // 0..8191
    const int b = wid >> 10;
    const int w10 = wid & 1023;
    const int tile = ((w10 & 3) << 8) | (w10 >> 2);  // quartile-spread
    const int sl = lane & 15, qi = lane >> 4;
    const float4* s4b = s4 + ((size_t)b << 12);
    const float* srb = srad + ((size_t)b << 12);
    const float* cminb = cminx + b * EST;
    const float* cmaxb = cmaxx + b * EST;

    const int qs = (tile << 2) + qi;                 // 4 consecutive queries
    const float4 q4v = s4b[qs];
    const float qx = -0.5f * q4v.x, qy = -0.5f * q4v.y, qz = -0.5f * q4v.z;
    const float qw = q4v.w;

    float k[10];
#pragma unroll
    for (int j = 0; j < 10; ++j) k[j] = __builtin_inff();

    const int c0 = qs >> 6;                          // uniform across wave
    const int hc0 = max(0, c0 - 1), hc1 = min(NCH - 1, c0 + 1);

    // ---- home scan (self excluded by index)
    for (int c = hc0; c <= hc1; ++c) {
        const int cb = c << 6;
#pragma unroll
        for (int i = 0; i < 4; ++i) {
            const int ci = cb + (i << 4) + sl;
            float4 cc = s4b[ci];
            float d2 = fmaf(cc.x, qx, fmaf(cc.y, qy, fmaf(cc.z, qz, qw + cc.w)));
            unsigned u = (__float_as_uint(d2) & 0xFFFFF000u) | (unsigned)ci;
            float uf = (ci == qs) ? __builtin_inff() : __uint_as_float(u);
            insert10(k, uf);
        }
    }

    // ---- exact home top-10 per query (4-round copy butterfly) -> window
    float t[10];
#pragma unroll
    for (int j = 0; j < 10; ++j) t[j] = k[j];
#pragma unroll
    for (int r = 0; r < 4; ++r) {
        float f[10];
#pragma unroll
        for (int j = 0; j < 10; ++j) f[j] = __shfl_xor(t[j], 1 << r, 64);
#pragma unroll
        for (int j = 0; j < 10; ++j) insert10(t, f[j]);
    }
    const float w = sqrtf(fmaxf(t[9], 0.f)) * 1.0002f;
    float lo = qx - w, hi = qx + w;
#pragma unroll
    for (int o = 32; o > 0; o >>= 1) {
        lo = fminf(lo, __shfl_xor(lo, o, 64));
        hi = fmaxf(hi, __shfl_xor(hi, o, 64));
    }

    // ---- outward right: chunks gated by uniform prefetched edges
    {
        int c = hc1 + 1;                       // <= 64
        float edge = cminb[c];
        while (edge <= hi) {                   // guard inf at 64/65
            float nedge = cminb[c + 1];
            const int cb = c << 6;
#pragma unroll
            for (int i = 0; i < 4; ++i) {
                const int ci = cb + (i << 4) + sl;
                float4 cc = s4b[ci];
                float d2 = fmaf(cc.x, qx, fmaf(cc.y, qy, fmaf(cc.z, qz, qw + cc.w)));
                unsigned u = (__float_as_uint(d2) & 0xFFFFF000u) | (unsigned)ci;
                insert10(k, __uint_as_float(u));
            }
            ++c; edge = nedge;
        }
    }
    // ---- outward left
    {
        int c = hc0 - 1;                       // >= -1
        float edge = cmaxb[c + 2];             // guard -inf at 0/1
        while (edge >= lo) {
            float nedge = cmaxb[c + 1];
            const int cb = c << 6;
#pragma unroll
            for (int i = 0; i < 4; ++i) {
                const int ci = cb + (i << 4) + sl;
                float4 cc = s4b[ci];
                float d2 = fmaf(cc.x, qx, fmaf(cc.y, qy, fmaf(cc.z, qz, qw + cc.w)));
                unsigned u = (__float_as_uint(d2) & 0xFFFFF000u) | (unsigned)ci;
                insert10(k, __uint_as_float(u));
            }
            --c; edge = nedge;
        }
    }

    // ---- final merge of 16 disjoint residue sets per query
#pragma unroll
    for (int r = 0; r < 4; ++r) {
        float f[10];
#pragma unroll
        for (int j = 0; j < 10; ++j) f[j] = __shfl_xor(k[j], 1 << r, 64);
#pragma unroll
        for (int j = 0; j < 10; ++j) insert10(k, f[j]);
    }

    if (sl == 0) {
        const float rn = srb[qs];
        float best = __builtin_inff();
#pragma unroll
        for (int j = 0; j < 10; ++j) {
            int m = (int)(__float_as_uint(k[j]) & 0xFFFu);
            float4 cc = s4b[m];
            float dx = fmaf(0.5f, cc.x, qx);
            float dy = fmaf(0.5f, cc.y, qy);
            float dz = fmaf(0.5f, cc.z, qz);
            float dis = sqrtf(fmaf(dx, dx, fmaf(dy, dy, dz * dz)));
            best = fminf(best, dis - (rn + srb[m]));
        }
        td[(b << 12) + qs] = best;  // sorted order; variance perm-invariant
    }
}

// ---------------- fused per-batch variance (ddof=1) + mean ----------------
__global__ __launch_bounds__(512)
void var_kernel(const float* __restrict__ td, float* __restrict__ out) {
    __shared__ float part[NB];
    const int lane = threadIdx.x & 63, s = threadIdx.x >> 6;  // wave s: batch s
    const float4* x4 = (const float4*)(td + ((size_t)s << 12));

    float sum = 0.f;
#pragma unroll
    for (int i = 0; i < 16; ++i) {
        float4 v = x4[lane + (i << 6)];
        sum += (v.x + v.y) + (v.z + v.w);
    }
#pragma unroll
    for (int o = 32; o > 0; o >>= 1) sum += __shfl_xor(sum, o, 64);
    const float mu = sum / (float)NN;

    float ss = 0.f;
#pragma unroll
    for (int i = 0; i < 16; ++i) {
        float4 v = x4[lane + (i << 6)];
        float d0 = v.x - mu, d1 = v.y - mu, d2 = v.z - mu, d3 = v.w - mu;
        ss = fmaf(d0, d0, ss); ss = fmaf(d1, d1, ss);
        ss = fmaf(d2, d2, ss); ss = fmaf(d3, d3, ss);
    }
#pragma unroll
    for (int o = 32; o > 0; o >>= 1) ss += __shfl_xor(ss, o, 64);
    if (lane == 0) part[s] = ss / (float)(NN - 1);
    __syncthreads();
    if (threadIdx.x == 0) {
        float tt = 0.f;
#pragma unroll
        for (int i = 0; i < NB; ++i) tt += part[i];
        out[0] = tt / (float)NB;
    }
}

extern "C" void kernel_launch(void* const* d_in, const int* in_sizes, int n_in,
                              void* d_out, int out_size, void* d_ws, size_t ws_size,
                              hipStream_t stream) {
    const float4* spheres = (const float4*)d_in[0];
    char* ws = (char*)d_ws;
    float4* s4    = (float4*)ws;                    // 524288 B
    float*  srad  = (float*)(ws + 524288);          // 131072 B
    float*  cminx = (float*)(ws + 655360);          //   4096 B
    float*  cmaxx = (float*)(ws + 659456);          //   4096 B
    float*  td    = (float*)(ws + 663552);          // 131072 B
    float*  out   = (float*)d_out;

    prep_kernel<<<dim3(512), dim3(256), 0, stream>>>(spheres, s4, srad, cminx, cmaxx);
    knn_kernel<<<dim3(2048), dim3(256), 0, stream>>>(s4, srad, cminx, cmaxx, td);
    var_kernel<<<dim3(1), dim3(512), 0, stream>>>(td, out);
}

// Round 9
// 100.352 us; speedup vs baseline: 1.8011x; 1.0358x over previous
//
#include <hip/hip_runtime.h>
#include <math.h>

// SphereInterLoss R9: exact 10-NN, x-sorted, static key-space window,
// tournament selection, prefetched counted scan, refillable grid.
//  prep_kernel: counting-rank by x -> prescaled sorted cloud
//               (-2x,-2y,-2z,|c|^2), radii, per-chunk x-edges.
//  knn_kernel : 128-thr blocks (2 waves) -> 4096 blocks, CU queue refills.
//               Wave = 4 consecutive sorted queries x 16 residue lanes.
//               Home scan (c0+-1, self by index) -> 10-pop tournament ->
//               exact home 10th key t9 per query. Chunk inclusion evaluated
//               lane-parallel (lane=chunk, trunc(gap^2)|0 <= t9, ballot) ->
//               counted ranges, 1-chunk software prefetch, __any-gated
//               inserts. Final 10-pop tournament broadcasts the top-10 keys;
//               all lanes evaluate sphere distances (independent loads).
//  var_kernel : fused per-batch var(ddof=1) + mean.
// Exactness: key = (d2 bits & ~0xFFF) | sorted idx (unique). Home t9 >=
// final t9; excluded chunk => every candidate key >= trunc(gap^2)|0 > t9.

#define NB 8
#define NN 4096
#define NCH 64
#define EST 66

#define INF __builtin_inff()

__device__ __forceinline__ float med3f(float a, float b, float c) {
    return __builtin_amdgcn_fmed3f(a, b, c);
}

// branchless insert into ascending k[0..9], dropping the max
__device__ __forceinline__ void insert10(float k[10], float u) {
#pragma unroll
    for (int j = 9; j >= 1; --j) k[j] = med3f(k[j - 1], k[j], u);
    k[0] = fminf(k[0], u);
}

// ---------------- prep: counting-rank by x + scatter ----------------
__global__ __launch_bounds__(256)
void prep_kernel(const float4* __restrict__ sp, float4* __restrict__ s4,
                 float* __restrict__ srad, float* __restrict__ cminx,
                 float* __restrict__ cmaxx) {
    __shared__ float xs[4 * 1028];               // 4 quarters, +4 pad each
    const int b = blockIdx.x >> 6, qt = blockIdx.x & 63;
    const int tid = threadIdx.x;
    const float4* spb = sp + ((size_t)b << 12);
    for (int j = tid; j < NN; j += 256)
        xs[(j >> 10) * 1028 + (j & 1023)] = spb[j].x;
    __syncthreads();

    const int e = (qt << 6) + (tid >> 2);        // element, 4 threads each
    const int part = tid & 3;
    const float xe = xs[(e >> 10) * 1028 + (e & 1023)];
    const float4* q4 = (const float4*)(xs + part * 1028);
    int cnt = 0;
    const int jb = part << 10;
#pragma unroll 4
    for (int i = 0; i < 256; ++i) {
        float4 v = q4[i];
        const int j0 = jb + (i << 2);
        cnt += (int)((v.x < xe) | ((v.x == xe) & (j0     < e)));
        cnt += (int)((v.y < xe) | ((v.y == xe) & (j0 + 1 < e)));
        cnt += (int)((v.z < xe) | ((v.z == xe) & (j0 + 2 < e)));
        cnt += (int)((v.w < xe) | ((v.w == xe) & (j0 + 3 < e)));
    }
    cnt += __shfl_xor(cnt, 1, 64);
    cnt += __shfl_xor(cnt, 2, 64);
    if (part == 0) {
        float4 s = spb[e];
        float w = fmaf(s.x, s.x, fmaf(s.y, s.y, s.z * s.z));
        const int r = cnt;                       // exact rank (permutation)
        s4[(b << 12) + r] = make_float4(-2.f * s.x, -2.f * s.y, -2.f * s.z, w);
        srad[(b << 12) + r] = s.w;
        if ((r & 63) == 0)  cminx[b * EST + (r >> 6)] = s.x;
        if ((r & 63) == 63) cmaxx[b * EST + (r >> 6) + 2] = s.x;
    }
}

// ---------------- knn ----------------
__global__ __launch_bounds__(128)
void knn_kernel(const float4* __restrict__ s4, const float* __restrict__ srad,
                const float* __restrict__ cminx, const float* __restrict__ cmaxx,
                float* __restrict__ td) {
    const int lane = threadIdx.x & 63;
    const int wid = (blockIdx.x << 1) | (threadIdx.x >> 6);   // 0..8191
    const int b = wid >> 10;
    const int w10 = wid & 1023;
    const int tile = ((w10 & 3) << 8) | (w10 >> 2);           // quartile-spread
    const int sl = lane & 15, qi = lane >> 4;
    const float4* s4b = s4 + ((size_t)b << 12);
    const float* srb = srad + ((size_t)b << 12);
    const float* cminb = cminx + b * EST;
    const float* cmaxb = cmaxx + b * EST + 2;

    const int qs = (tile << 2) + qi;                 // 4 consecutive queries
    const float4 q4v = s4b[qs];
    const float qx = -0.5f * q4v.x, qy = -0.5f * q4v.y, qz = -0.5f * q4v.z;
    const float qw = q4v.w;

    float k[10];
#pragma unroll
    for (int j = 0; j < 10; ++j) k[j] = INF;

    const int c0 = qs >> 6;                          // uniform across wave
    const int hc0 = max(0, c0 - 1), hc1 = min(NCH - 1, c0 + 1);

    // ---- home scan (self excluded by index)
    for (int c = hc0; c <= hc1; ++c) {
        const int cb = c << 6;
#pragma unroll
        for (int i = 0; i < 4; ++i) {
            const int ci = cb + (i << 4) + sl;
            float4 cc = s4b[ci];
            float d2 = fmaf(cc.x, qx, fmaf(cc.y, qy, fmaf(cc.z, qz, qw + cc.w)));
            unsigned u = (__float_as_uint(d2) & 0xFFFFF000u) | (unsigned)ci;
            float uf = (ci == qs) ? INF : __uint_as_float(u);
            insert10(k, uf);
        }
    }

    // ---- home exact 10th key per query: 10-pop tournament on a copy
    float t9;
    {
        float h[10];
#pragma unroll
        for (int j = 0; j < 10; ++j) h[j] = k[j];
        float g = 0.f;
#pragma unroll
        for (int p = 0; p < 10; ++p) {
            g = h[0];
            g = fminf(g, __shfl_xor(g, 1, 64));
            g = fminf(g, __shfl_xor(g, 2, 64));
            g = fminf(g, __shfl_xor(g, 4, 64));
            g = fminf(g, __shfl_xor(g, 8, 64));
            const bool own = (h[0] == g);
#pragma unroll
            for (int j = 0; j < 9; ++j) h[j] = own ? h[j + 1] : h[j];
            h[9] = own ? INF : h[9];
        }
        t9 = g;
    }

    // ---- lane-parallel chunk inclusion (lane = chunk id), key-space exact
    const float qxg0 = __shfl(qx, 0, 64),  t9g0 = __shfl(t9, 0, 64);
    const float qxg1 = __shfl(qx, 16, 64), t9g1 = __shfl(t9, 16, 64);
    const float qxg2 = __shfl(qx, 32, 64), t9g2 = __shfl(t9, 32, 64);
    const float qxg3 = __shfl(qx, 48, 64), t9g3 = __shfl(t9, 48, 64);

    auto incq = [](float gap, float t9q) {
        gap = fmaxf(gap, 0.f);
        float g2t = __uint_as_float(__float_as_uint(gap * gap) & 0xFFFFF000u);
        return g2t <= t9q;
    };
    const int lc = lane;
    const float cminc = cminb[lc];
    const float cmaxc = cmaxb[lc];
    const bool incR = (lc > hc1) &&
        (incq(cminc - qxg0, t9g0) || incq(cminc - qxg1, t9g1) ||
         incq(cminc - qxg2, t9g2) || incq(cminc - qxg3, t9g3));
    const bool incL = (lc < hc0) &&
        (incq(qxg0 - cmaxc, t9g0) || incq(qxg1 - cmaxc, t9g1) ||
         incq(qxg2 - cmaxc, t9g2) || incq(qxg3 - cmaxc, t9g3));
    const unsigned long long mR = __ballot(incR);
    const unsigned long long mL = __ballot(incL);
    const int cHi = mR ? (63 - __clzll((long long)mR)) : hc1;
    const int cLo = mL ? (__ffsll((unsigned long long)mL) - 1) : hc0;

    // ---- counted outward scan, 1-chunk prefetch, __any-gated inserts
    auto scan_range = [&](int ca, int cz) {
        if (ca > cz) return;
        int pb = ca << 6;
        float4 cA = s4b[pb + sl];
        float4 cB = s4b[pb + 16 + sl];
        float4 cC = s4b[pb + 32 + sl];
        float4 cD = s4b[pb + 48 + sl];
        for (int c = ca; c <= cz; ++c) {
            const int nb = min(c + 1, cz) << 6;
            float4 nA = s4b[nb + sl];
            float4 nB = s4b[nb + 16 + sl];
            float4 nC = s4b[nb + 32 + sl];
            float4 nD = s4b[nb + 48 + sl];
            const int cb = c << 6;
            float dA = fmaf(cA.x, qx, fmaf(cA.y, qy, fmaf(cA.z, qz, qw + cA.w)));
            float dB = fmaf(cB.x, qx, fmaf(cB.y, qy, fmaf(cB.z, qz, qw + cB.w)));
            float dC = fmaf(cC.x, qx, fmaf(cC.y, qy, fmaf(cC.z, qz, qw + cC.w)));
            float dD = fmaf(cD.x, qx, fmaf(cD.y, qy, fmaf(cD.z, qz, qw + cD.w)));
            float fA = __uint_as_float((__float_as_uint(dA) & 0xFFFFF000u) | (unsigned)(cb + sl));
            float fB = __uint_as_float((__float_as_uint(dB) & 0xFFFFF000u) | (unsigned)(cb + 16 + sl));
            float fC = __uint_as_float((__float_as_uint(dC) & 0xFFFFF000u) | (unsigned)(cb + 32 + sl));
            float fD = __uint_as_float((__float_as_uint(dD) & 0xFFFFF000u) | (unsigned)(cb + 48 + sl));
            float kmin = fminf(fminf(fA, fB), fminf(fC, fD));
            if (__any(kmin < k[9])) {
                insert10(k, fA); insert10(k, fB);
                insert10(k, fC); insert10(k, fD);
            }
            cA = nA; cB = nB; cC = nC; cD = nD;
        }
    };
    scan_range(cLo, hc0 - 1);
    scan_range(hc1 + 1, cHi);

    // ---- final 10-pop tournament: broadcasts top-10 keys to all lanes
    float t[10];
#pragma unroll
    for (int p = 0; p < 10; ++p) {
        float g = k[0];
        g = fminf(g, __shfl_xor(g, 1, 64));
        g = fminf(g, __shfl_xor(g, 2, 64));
        g = fminf(g, __shfl_xor(g, 4, 64));
        g = fminf(g, __shfl_xor(g, 8, 64));
        const bool own = (k[0] == g);
#pragma unroll
        for (int j = 0; j < 9; ++j) k[j] = own ? k[j + 1] : k[j];
        k[9] = own ? INF : k[9];
        t[p] = g;
    }

    // ---- all lanes evaluate the 10 winners (independent pipelined loads)
    const float rn = srb[qs];
    float best = INF;
#pragma unroll
    for (int j = 0; j < 10; ++j) {
        const int m = (int)(__float_as_uint(t[j]) & 0xFFFu);
        float4 cc = s4b[m];
        float dx = fmaf(0.5f, cc.x, qx);
        float dy = fmaf(0.5f, cc.y, qy);
        float dz = fmaf(0.5f, cc.z, qz);
        float dis = sqrtf(fmaf(dx, dx, fmaf(dy, dy, dz * dz)));
        best = fminf(best, dis - (rn + srb[m]));
    }
    if (sl == 0) td[(b << 12) + qs] = best;   // sorted order; var perm-invariant
}

// ---------------- fused per-batch variance (ddof=1) + mean ----------------
__global__ __launch_bounds__(512)
void var_kernel(const float* __restrict__ td, float* __restrict__ out) {
    __shared__ float part[NB];
    const int lane = threadIdx.x & 63, s = threadIdx.x >> 6;  // wave s: batch s
    const float4* x4 = (const float4*)(td + ((size_t)s << 12));

    float sum = 0.f;
#pragma unroll
    for (int i = 0; i < 16; ++i) {
        float4 v = x4[lane + (i << 6)];
        sum += (v.x + v.y) + (v.z + v.w);
    }
#pragma unroll
    for (int o = 32; o > 0; o >>= 1) sum += __shfl_xor(sum, o, 64);
    const float mu = sum / (float)NN;

    float ss = 0.f;
#pragma unroll
    for (int i = 0; i < 16; ++i) {
        float4 v = x4[lane + (i << 6)];
        float d0 = v.x - mu, d1 = v.y - mu, d2 = v.z - mu, d3 = v.w - mu;
        ss = fmaf(d0, d0, ss); ss = fmaf(d1, d1, ss);
        ss = fmaf(d2, d2, ss); ss = fmaf(d3, d3, ss);
    }
#pragma unroll
    for (int o = 32; o > 0; o >>= 1) ss += __shfl_xor(ss, o, 64);
    if (lane == 0) part[s] = ss / (float)(NN - 1);
    __syncthreads();
    if (threadIdx.x == 0) {
        float tt = 0.f;
#pragma unroll
        for (int i = 0; i < NB; ++i) tt += part[i];
        out[0] = tt / (float)NB;
    }
}

extern "C" void kernel_launch(void* const* d_in, const int* in_sizes, int n_in,
                              void* d_out, int out_size, void* d_ws, size_t ws_size,
                              hipStream_t stream) {
    const float4* spheres = (const float4*)d_in[0];
    char* ws = (char*)d_ws;
    float4* s4    = (float4*)ws;                    // 524288 B
    float*  srad  = (float*)(ws + 524288);          // 131072 B
    float*  cminx = (float*)(ws + 655360);          //   4096 B
    float*  cmaxx = (float*)(ws + 659456);          //   4096 B
    float*  td    = (float*)(ws + 663552);          // 131072 B
    float*  out   = (float*)d_out;

    prep_kernel<<<dim3(512), dim3(256), 0, stream>>>(spheres, s4, srad, cminx, cmaxx);
    knn_kernel<<<dim3(4096), dim3(128), 0, stream>>>(s4, srad, cminx, cmaxx, td);
    var_kernel<<<dim3(1), dim3(512), 0, stream>>>(td, out);
}